// Round 1
// baseline (227.490 us; speedup 1.0000x reference)
//
#include <hip/hip_runtime.h>

typedef unsigned short u16;
typedef float f32x4 __attribute__((ext_vector_type(4)));
typedef __bf16 bf16x8 __attribute__((ext_vector_type(8)));
typedef u16 u16x8 __attribute__((ext_vector_type(8)));

#define ATT_SCALE 0.0125f  // 0.1 / sqrt(64)

__device__ __forceinline__ u16 f2bf(float x) {
  unsigned u = __builtin_bit_cast(unsigned, x);
  u += 0x7fffu + ((u >> 16) & 1u);  // RNE
  return (u16)(u >> 16);
}

__device__ __forceinline__ f32x4 mfma16(u16x8 a, u16x8 b, f32x4 c) {
  return __builtin_amdgcn_mfma_f32_16x16x32_bf16(
      __builtin_bit_cast(bf16x8, a), __builtin_bit_cast(bf16x8, b), c, 0, 0, 0);
}

__device__ __forceinline__ void gl_lds16(const void* g, void* l) {
  __builtin_amdgcn_global_load_lds(
      (__attribute__((address_space(1))) void*)g,
      (__attribute__((address_space(3))) void*)l, 16, 0, 0);
}

// ---------------- convert fp32 -> bf16 ----------------
__global__ void k_convert(const float* __restrict__ in, u16* __restrict__ out, int n) {
  int stride = gridDim.x * blockDim.x * 4;
  for (int i = (blockIdx.x * blockDim.x + threadIdx.x) * 4; i < n; i += stride) {
    float4 v = *(const float4*)&in[i];
    ushort4 o;
    o.x = f2bf(v.x); o.y = f2bf(v.y); o.z = f2bf(v.z); o.w = f2bf(v.w);
    *(ushort4*)&out[i] = o;
  }
}

// ---------------- transpose fp32[rows][cols] -> bf16[cols][rows] ----------------
__global__ void k_transpose(const float* __restrict__ in, u16* __restrict__ out,
                            int rows, int cols) {
  __shared__ float tile[32][33];
  int n0 = blockIdx.x * 32;  // col block
  int k0 = blockIdx.y * 32;  // row block
  int tx = threadIdx.x, ty = threadIdx.y;  // (32, 8)
#pragma unroll
  for (int i = 0; i < 32; i += 8)
    tile[ty + i][tx] = in[(size_t)(k0 + ty + i) * cols + n0 + tx];
  __syncthreads();
#pragma unroll
  for (int i = 0; i < 32; i += 8)
    out[(size_t)(n0 + ty + i) * rows + k0 + tx] = f2bf(tile[tx][ty + i]);
}

// ---------------- GEMM1: qkv = x @ W_attn + b_attn, scatter to q/k/vT bf16 ----------------
// A [4096][1024] bf16, Bt [3072][1024] bf16 (W_attn^T)
__global__ void k_gemm_qkv(const u16* __restrict__ A, const u16* __restrict__ Bt,
                           const float* __restrict__ bias,
                           u16* __restrict__ qb, u16* __restrict__ kb, u16* __restrict__ vTb) {
  __shared__ u16 Al[128 * 64];
  __shared__ u16 Bl[128 * 64];
  const int tid = threadIdx.x;
  const int lane = tid & 63;
  const int w = tid >> 6;
  const int m0 = blockIdx.y * 128;
  const int n0 = blockIdx.x * 128;
  const int wr = (w >> 1) * 64;
  const int wc = (w & 1) * 64;
  const int lr = lane & 15;
  const int lk = (lane >> 4) * 8;

  f32x4 acc[4][4] = {};

  for (int k0 = 0; k0 < 1024; k0 += 64) {
#pragma unroll
    for (int it = 0; it < 4; ++it) {
      int off = (it * 256 + tid) * 8;
      int r = off >> 6, c = off & 63;
      gl_lds16(&A[(size_t)(m0 + r) * 1024 + k0 + c], &Al[off]);
      gl_lds16(&Bt[(size_t)(n0 + r) * 1024 + k0 + c], &Bl[off]);
    }
    __syncthreads();
#pragma unroll
    for (int kk = 0; kk < 64; kk += 32) {
      u16x8 af[4], bf[4];
#pragma unroll
      for (int i = 0; i < 4; ++i) {
        af[i] = *(const u16x8*)&Al[(wr + i * 16 + lr) * 64 + kk + lk];
        bf[i] = *(const u16x8*)&Bl[(wc + i * 16 + lr) * 64 + kk + lk];
      }
#pragma unroll
      for (int i = 0; i < 4; ++i)
#pragma unroll
        for (int j = 0; j < 4; ++j)
          acc[i][j] = mfma16(af[i], bf[j], acc[i][j]);
    }
    __syncthreads();
  }

#pragma unroll
  for (int i = 0; i < 4; ++i) {
    int rowb = m0 + wr + i * 16 + ((lane >> 4) << 2);
#pragma unroll
    for (int j = 0; j < 4; ++j) {
      int col = n0 + wc + j * 16 + lr;
      float bv = bias[col];
      int which = col >> 10;
      int c = col & 1023;
      int h = c >> 6, d = c & 63;
#pragma unroll
      for (int r = 0; r < 4; ++r) {
        int row = rowb + r;
        int b_ = row >> 11, t = row & 2047;
        int bh = b_ * 16 + h;
        u16 val = f2bf(acc[i][j][r] + bv);
        if (which == 0)      qb[((size_t)bh * 2048 + t) * 64 + d] = val;
        else if (which == 1) kb[((size_t)bh * 2048 + t) * 64 + d] = val;
        else                 vTb[((size_t)bh * 64 + d) * 2048 + t] = val;
      }
    }
  }
}

// ---------------- flash attention ----------------
// qb,kb: [32][2048][64] bf16 ; vTb: [32][64][2048] bf16 ; yb: [4096][1024] bf16
__global__ void k_attn(const u16* __restrict__ qb, const u16* __restrict__ kb,
                       const u16* __restrict__ vTb, u16* __restrict__ yb) {
  __shared__ u16 Kl[64 * 64];
  __shared__ u16 Vl[64 * 64];      // transposed [d][kv]
  __shared__ u16 Pl[4][16][64];

  const int tid = threadIdx.x, lane = tid & 63, w = tid >> 6;
  const int qt = blockIdx.x;       // 0..31
  const int bh = blockIdx.y;       // 0..31
  const int b_ = bh >> 4, h = bh & 15;
  const int lr = lane & 15;
  const int lk = (lane >> 4) * 8;
  const int q0 = qt * 64 + w * 16; // wave's first q row

  // Q fragments (held in registers the whole kernel)
  const u16* qrow = qb + ((size_t)bh * 2048 + q0 + lr) * 64;
  u16x8 qf[2];
  qf[0] = *(const u16x8*)&qrow[lk];
  qf[1] = *(const u16x8*)&qrow[32 + lk];

  f32x4 o[4] = {};
  float mrow[4], lrow[4];
#pragma unroll
  for (int r = 0; r < 4; ++r) { mrow[r] = -1e30f; lrow[r] = 0.f; }

  const int nkv = qt + 1;
  for (int kv = 0; kv < nkv; ++kv) {
    int kv0 = kv * 64;
    // stage K [kv][d] and V^T [d][kv] tiles (64x64 each)
#pragma unroll
    for (int it = 0; it < 2; ++it) {
      int off = (it * 256 + tid) * 8;
      int r = off >> 6, c = off & 63;
      gl_lds16(&kb[((size_t)bh * 2048 + kv0 + r) * 64 + c], &Kl[off]);
      gl_lds16(&vTb[((size_t)bh * 64 + r) * 2048 + kv0 + c], &Vl[off]);
    }
    __syncthreads();

    // S = Q K^T   (16 q-rows x 64 keys per wave)
    f32x4 s[4] = {};
#pragma unroll
    for (int kk = 0; kk < 2; ++kk) {
#pragma unroll
      for (int n = 0; n < 4; ++n) {
        u16x8 kf = *(const u16x8*)&Kl[(n * 16 + lr) * 64 + kk * 32 + lk];
        s[n] = mfma16(qf[kk], kf, s[n]);
      }
    }

    // online softmax
    float p[4][4], tmax[4];
#pragma unroll
    for (int r = 0; r < 4; ++r) tmax[r] = -1e30f;
#pragma unroll
    for (int n = 0; n < 4; ++n) {
      int kvg = kv0 + n * 16 + lr;
#pragma unroll
      for (int r = 0; r < 4; ++r) {
        int qg = q0 + (lane >> 4) * 4 + r;
        float v = (kvg <= qg) ? s[n][r] * ATT_SCALE : -1e30f;
        p[n][r] = v;
        tmax[r] = fmaxf(tmax[r], v);
      }
    }
#pragma unroll
    for (int mks = 1; mks < 16; mks <<= 1)
#pragma unroll
      for (int r = 0; r < 4; ++r) tmax[r] = fmaxf(tmax[r], __shfl_xor(tmax[r], mks, 64));

    float alpha[4];
#pragma unroll
    for (int r = 0; r < 4; ++r) {
      float mn = fmaxf(mrow[r], tmax[r]);
      alpha[r] = __expf(mrow[r] - mn);
      mrow[r] = mn;
    }
    float lsum[4] = {0.f, 0.f, 0.f, 0.f};
#pragma unroll
    for (int n = 0; n < 4; ++n)
#pragma unroll
      for (int r = 0; r < 4; ++r) {
        float e = __expf(p[n][r] - mrow[r]);
        p[n][r] = e;
        lsum[r] += e;
      }
#pragma unroll
    for (int mks = 1; mks < 16; mks <<= 1)
#pragma unroll
      for (int r = 0; r < 4; ++r) lsum[r] += __shfl_xor(lsum[r], mks, 64);
#pragma unroll
    for (int r = 0; r < 4; ++r) lrow[r] = lrow[r] * alpha[r] + lsum[r];
#pragma unroll
    for (int dt = 0; dt < 4; ++dt)
#pragma unroll
      for (int r = 0; r < 4; ++r) o[dt][r] *= alpha[r];

    // P -> bf16 via wave-private LDS (layout fix for A-fragment)
#pragma unroll
    for (int n = 0; n < 4; ++n)
#pragma unroll
      for (int r = 0; r < 4; ++r)
        Pl[w][(lane >> 4) * 4 + r][n * 16 + lr] = f2bf(p[n][r]);
    __syncthreads();

    // O += P V
#pragma unroll
    for (int kk = 0; kk < 2; ++kk) {
      u16x8 pf = *(const u16x8*)&Pl[w][lr][kk * 32 + lk];
#pragma unroll
      for (int dt = 0; dt < 4; ++dt) {
        u16x8 vf = *(const u16x8*)&Vl[(dt * 16 + lr) * 64 + kk * 32 + lk];
        o[dt] = mfma16(pf, vf, o[dt]);
      }
    }
    __syncthreads();
  }

  // epilogue: y = O / l, store bf16 [b*2048+t][h*64+d]
#pragma unroll
  for (int dt = 0; dt < 4; ++dt) {
#pragma unroll
    for (int r = 0; r < 4; ++r) {
      int t = q0 + (lane >> 4) * 4 + r;
      int d = dt * 16 + lr;
      yb[((size_t)b_ * 2048 + t) * 1024 + h * 64 + d] = f2bf(o[dt][r] / lrow[r]);
    }
  }
}

// ---------------- GEMM2: out = y @ W_proj + b_proj (fp32 out) ----------------
__global__ void k_gemm_out(const u16* __restrict__ A, const u16* __restrict__ Bt,
                           const float* __restrict__ bias, float* __restrict__ out) {
  __shared__ u16 Al[128 * 64];
  __shared__ u16 Bl[128 * 64];
  const int tid = threadIdx.x;
  const int lane = tid & 63;
  const int w = tid >> 6;
  const int m0 = blockIdx.y * 128;
  const int n0 = blockIdx.x * 128;
  const int wr = (w >> 1) * 64;
  const int wc = (w & 1) * 64;
  const int lr = lane & 15;
  const int lk = (lane >> 4) * 8;

  f32x4 acc[4][4] = {};

  for (int k0 = 0; k0 < 1024; k0 += 64) {
#pragma unroll
    for (int it = 0; it < 4; ++it) {
      int off = (it * 256 + tid) * 8;
      int r = off >> 6, c = off & 63;
      gl_lds16(&A[(size_t)(m0 + r) * 1024 + k0 + c], &Al[off]);
      gl_lds16(&Bt[(size_t)(n0 + r) * 1024 + k0 + c], &Bl[off]);
    }
    __syncthreads();
#pragma unroll
    for (int kk = 0; kk < 64; kk += 32) {
      u16x8 af[4], bf[4];
#pragma unroll
      for (int i = 0; i < 4; ++i) {
        af[i] = *(const u16x8*)&Al[(wr + i * 16 + lr) * 64 + kk + lk];
        bf[i] = *(const u16x8*)&Bl[(wc + i * 16 + lr) * 64 + kk + lk];
      }
#pragma unroll
      for (int i = 0; i < 4; ++i)
#pragma unroll
        for (int j = 0; j < 4; ++j)
          acc[i][j] = mfma16(af[i], bf[j], acc[i][j]);
    }
    __syncthreads();
  }

#pragma unroll
  for (int i = 0; i < 4; ++i) {
    int rowb = m0 + wr + i * 16 + ((lane >> 4) << 2);
#pragma unroll
    for (int j = 0; j < 4; ++j) {
      int col = n0 + wc + j * 16 + lr;
      float bv = bias[col];
#pragma unroll
      for (int r = 0; r < 4; ++r)
        out[(size_t)(rowb + r) * 1024 + col] = acc[i][j][r] + bv;
    }
  }
}

extern "C" void kernel_launch(void* const* d_in, const int* in_sizes, int n_in,
                              void* d_out, int out_size, void* d_ws, size_t ws_size,
                              hipStream_t stream) {
  const float* x      = (const float*)d_in[0];
  const float* W_attn = (const float*)d_in[1];
  const float* b_attn = (const float*)d_in[2];
  const float* W_proj = (const float*)d_in[3];
  const float* b_proj = (const float*)d_in[4];
  float* out = (float*)d_out;

  char* ws = (char*)d_ws;
  const size_t MB = 1024 * 1024;
  u16* x_bf  = (u16*)(ws);             // 4096*1024   (8 MB)
  u16* Wt_a  = (u16*)(ws + 8 * MB);    // 3072*1024   (6 MB)
  u16* Wt_p  = (u16*)(ws + 14 * MB);   // 1024*1024   (2 MB)
  u16* qbf   = (u16*)(ws + 16 * MB);   // 32*2048*64  (8 MB)
  u16* kbf   = (u16*)(ws + 24 * MB);   // 32*2048*64  (8 MB)
  u16* vTbf  = (u16*)(ws + 32 * MB);   // 32*64*2048  (8 MB)
  u16* ybf   = (u16*)(ws + 40 * MB);   // 4096*1024   (8 MB)

  k_convert<<<2048, 256, 0, stream>>>(x, x_bf, 4096 * 1024);
  k_transpose<<<dim3(96, 32), dim3(32, 8), 0, stream>>>(W_attn, Wt_a, 1024, 3072);
  k_transpose<<<dim3(32, 32), dim3(32, 8), 0, stream>>>(W_proj, Wt_p, 1024, 1024);
  k_gemm_qkv<<<dim3(24, 32), 256, 0, stream>>>(x_bf, Wt_a, b_attn, qbf, kbf, vTbf);
  k_attn<<<dim3(32, 32), 256, 0, stream>>>(qbf, kbf, vTbf, ybf);
  k_gemm_out<<<dim3(8, 32), 256, 0, stream>>>(ybf, Wt_p, b_proj, out);
}

// Round 2
// 187.334 us; speedup vs baseline: 1.2144x; 1.2144x over previous
//
#include <hip/hip_runtime.h>

typedef unsigned short u16;
typedef float f32x4 __attribute__((ext_vector_type(4)));
typedef __bf16 bf16x8 __attribute__((ext_vector_type(8)));
typedef u16 u16x8 __attribute__((ext_vector_type(8)));

#define ATT_SCALE 0.0125f  // 0.1 / sqrt(64)

__device__ __forceinline__ u16 f2bf(float x) {
  unsigned u = __builtin_bit_cast(unsigned, x);
  u += 0x7fffu + ((u >> 16) & 1u);  // RNE
  return (u16)(u >> 16);
}

__device__ __forceinline__ f32x4 mfma16(u16x8 a, u16x8 b, f32x4 c) {
  return __builtin_amdgcn_mfma_f32_16x16x32_bf16(
      __builtin_bit_cast(bf16x8, a), __builtin_bit_cast(bf16x8, b), c, 0, 0, 0);
}

__device__ __forceinline__ void gl_lds16(const void* g, void* l) {
  __builtin_amdgcn_global_load_lds(
      (__attribute__((address_space(1))) void*)g,
      (__attribute__((address_space(3))) void*)l, 16, 0, 0);
}

// ---------------- convert fp32 -> bf16 ----------------
__global__ void k_convert(const float* __restrict__ in, u16* __restrict__ out, int n) {
  int stride = gridDim.x * blockDim.x * 4;
  for (int i = (blockIdx.x * blockDim.x + threadIdx.x) * 4; i < n; i += stride) {
    float4 v = *(const float4*)&in[i];
    ushort4 o;
    o.x = f2bf(v.x); o.y = f2bf(v.y); o.z = f2bf(v.z); o.w = f2bf(v.w);
    *(ushort4*)&out[i] = o;
  }
}

// ---------------- transpose fp32[rows][cols] -> bf16[cols][rows] ----------------
__global__ void k_transpose(const float* __restrict__ in, u16* __restrict__ out,
                            int rows, int cols) {
  __shared__ float tile[32][33];
  int n0 = blockIdx.x * 32;  // col block
  int k0 = blockIdx.y * 32;  // row block
  int tx = threadIdx.x, ty = threadIdx.y;  // (32, 8)
#pragma unroll
  for (int i = 0; i < 32; i += 8)
    tile[ty + i][tx] = in[(size_t)(k0 + ty + i) * cols + n0 + tx];
  __syncthreads();
#pragma unroll
  for (int i = 0; i < 32; i += 8)
    out[(size_t)(n0 + ty + i) * rows + k0 + tx] = f2bf(tile[tx][ty + i]);
}

// ---------------- GEMM1: qkv = x @ W_attn + b_attn, scatter to q/k/vT bf16 ----------------
// A [4096][1024] bf16, Bt [3072][1024] bf16 (W_attn^T)
// Q is pre-scaled by ATT_SCALE at f32 precision.
__global__ void k_gemm_qkv(const u16* __restrict__ A, const u16* __restrict__ Bt,
                           const float* __restrict__ bias,
                           u16* __restrict__ qb, u16* __restrict__ kb, u16* __restrict__ vTb) {
  __shared__ u16 Al[128 * 64];
  __shared__ u16 Bl[128 * 64];
  const int tid = threadIdx.x;
  const int lane = tid & 63;
  const int w = tid >> 6;
  const int m0 = blockIdx.y * 128;
  const int n0 = blockIdx.x * 128;
  const int wr = (w >> 1) * 64;
  const int wc = (w & 1) * 64;
  const int lr = lane & 15;
  const int lk = (lane >> 4) * 8;

  f32x4 acc[4][4] = {};

  for (int k0 = 0; k0 < 1024; k0 += 64) {
#pragma unroll
    for (int it = 0; it < 4; ++it) {
      int off = (it * 256 + tid) * 8;
      int r = off >> 6, c = off & 63;
      gl_lds16(&A[(size_t)(m0 + r) * 1024 + k0 + c], &Al[off]);
      gl_lds16(&Bt[(size_t)(n0 + r) * 1024 + k0 + c], &Bl[off]);
    }
    __syncthreads();
#pragma unroll
    for (int kk = 0; kk < 64; kk += 32) {
      u16x8 af[4], bf[4];
#pragma unroll
      for (int i = 0; i < 4; ++i) {
        af[i] = *(const u16x8*)&Al[(wr + i * 16 + lr) * 64 + kk + lk];
        bf[i] = *(const u16x8*)&Bl[(wc + i * 16 + lr) * 64 + kk + lk];
      }
#pragma unroll
      for (int i = 0; i < 4; ++i)
#pragma unroll
        for (int j = 0; j < 4; ++j)
          acc[i][j] = mfma16(af[i], bf[j], acc[i][j]);
    }
    __syncthreads();
  }

#pragma unroll
  for (int i = 0; i < 4; ++i) {
    int rowb = m0 + wr + i * 16 + ((lane >> 4) << 2);
#pragma unroll
    for (int j = 0; j < 4; ++j) {
      int col = n0 + wc + j * 16 + lr;
      float bv = bias[col];
      int which = col >> 10;
      int c = col & 1023;
      int h = c >> 6, d = c & 63;
#pragma unroll
      for (int r = 0; r < 4; ++r) {
        int row = rowb + r;
        int b_ = row >> 11, t = row & 2047;
        int bh = b_ * 16 + h;
        float fv = acc[i][j][r] + bv;
        if (which == 0) {
          qb[((size_t)bh * 2048 + t) * 64 + d] = f2bf(fv * ATT_SCALE);
        } else if (which == 1) {
          kb[((size_t)bh * 2048 + t) * 64 + d] = f2bf(fv);
        } else {
          vTb[((size_t)bh * 64 + d) * 2048 + t] = f2bf(fv);
        }
      }
    }
  }
}

// ---------------- flash attention ----------------
// qb,kb: [32][2048][64] bf16 ; vTb: [32][64][2048] bf16 ; yb: [4096][1024] bf16
// K/V/P LDS tiles XOR-swizzled: 16B chunk c at row r holds global chunk c^(r&7).
__device__ __forceinline__ void stage_kv(const u16* __restrict__ kb_bh,
                                         const u16* __restrict__ vT_bh,
                                         u16* Kd, u16* Vd, int kv0, int tid) {
#pragma unroll
  for (int it = 0; it < 2; ++it) {
    int ch = it * 256 + tid;          // 16B-chunk index 0..511 (64 rows x 8 chunks)
    int r = ch >> 3, c = ch & 7;
    int sc = c ^ (r & 7);             // pre-swizzled global source chunk
    gl_lds16(&kb_bh[(size_t)(kv0 + r) * 64 + sc * 8], &Kd[ch * 8]);
    gl_lds16(&vT_bh[(size_t)r * 2048 + kv0 + sc * 8], &Vd[ch * 8]);
  }
}

__global__ void k_attn(const u16* __restrict__ qb, const u16* __restrict__ kb,
                       const u16* __restrict__ vTb, u16* __restrict__ yb) {
  __shared__ u16 Kl[2][4096];
  __shared__ u16 Vl[2][4096];      // transposed [d][kv]
  __shared__ u16 Pl[4][1024];      // per-wave [16 q][64 kv], swizzled

  const int tid = threadIdx.x, lane = tid & 63, w = tid >> 6;
  const int xx = blockIdx.x;
  const int qt = (xx & 1) ? (xx >> 1) : (31 - (xx >> 1));  // heavy/light pairing
  const int bh = blockIdx.y;       // 0..31
  const int b_ = bh >> 4, h = bh & 15;
  const int lr = lane & 15;
  const int g = lane >> 4;
  const int lk = g * 8;
  const int q0 = qt * 64 + w * 16; // wave's first q row

  const u16* kb_bh = kb + (size_t)bh * 2048 * 64;
  const u16* vT_bh = vTb + (size_t)bh * 64 * 2048;

  // Q fragments (held in registers the whole kernel; pre-scaled by ATT_SCALE)
  const u16* qrow = qb + ((size_t)bh * 2048 + q0 + lr) * 64;
  u16x8 qf[2];
  qf[0] = *(const u16x8*)&qrow[lk];
  qf[1] = *(const u16x8*)&qrow[32 + lk];

  f32x4 o[4] = {};
  float mrow[4], lrow[4];
#pragma unroll
  for (int r = 0; r < 4; ++r) { mrow[r] = -1e30f; lrow[r] = 0.f; }

  const int nkv = qt + 1;
  stage_kv(kb_bh, vT_bh, Kl[0], Vl[0], 0, tid);
  __syncthreads();
  int cur = 0;

  for (int kv = 0; kv < nkv; ++kv) {
    // prefetch next tile into the other buffer (stays in flight across compute)
    if (kv + 1 < nkv)
      stage_kv(kb_bh, vT_bh, Kl[cur ^ 1], Vl[cur ^ 1], (kv + 1) * 64, tid);

    const u16* Kc = Kl[cur];
    const u16* Vc = Vl[cur];
    const int kv0 = kv * 64;

    // S = Q K^T   (16 q-rows x 64 keys per wave)
    f32x4 s[4] = {};
#pragma unroll
    for (int kk = 0; kk < 2; ++kk) {
#pragma unroll
      for (int n = 0; n < 4; ++n) {
        int kr = n * 16 + lr;
        u16x8 kf = *(const u16x8*)&Kc[kr * 64 + (((kk * 4 + g) ^ (kr & 7)) * 8)];
        s[n] = mfma16(qf[kk], kf, s[n]);
      }
    }

    // online softmax (scale already folded into Q)
    float p[4][4], tmax[4];
#pragma unroll
    for (int r = 0; r < 4; ++r) tmax[r] = -1e30f;
#pragma unroll
    for (int n = 0; n < 4; ++n) {
      int kvg = kv0 + n * 16 + lr;
#pragma unroll
      for (int r = 0; r < 4; ++r) {
        int qg = q0 + g * 4 + r;
        float v = (kvg <= qg) ? s[n][r] : -1e30f;
        p[n][r] = v;
        tmax[r] = fmaxf(tmax[r], v);
      }
    }
#pragma unroll
    for (int mks = 1; mks < 16; mks <<= 1)
#pragma unroll
      for (int r = 0; r < 4; ++r) tmax[r] = fmaxf(tmax[r], __shfl_xor(tmax[r], mks, 64));

    float alpha[4];
#pragma unroll
    for (int r = 0; r < 4; ++r) {
      float mn = fmaxf(mrow[r], tmax[r]);
      alpha[r] = __expf(mrow[r] - mn);
      mrow[r] = mn;
    }
    float lsum[4] = {0.f, 0.f, 0.f, 0.f};
#pragma unroll
    for (int n = 0; n < 4; ++n)
#pragma unroll
      for (int r = 0; r < 4; ++r) {
        float e = __expf(p[n][r] - mrow[r]);
        p[n][r] = e;
        lsum[r] += e;
      }
#pragma unroll
    for (int mks = 1; mks < 16; mks <<= 1)
#pragma unroll
      for (int r = 0; r < 4; ++r) lsum[r] += __shfl_xor(lsum[r], mks, 64);
#pragma unroll
    for (int r = 0; r < 4; ++r) lrow[r] = lrow[r] * alpha[r] + lsum[r];
#pragma unroll
    for (int dt = 0; dt < 4; ++dt)
#pragma unroll
      for (int r = 0; r < 4; ++r) o[dt][r] *= alpha[r];

    // P -> bf16 into wave-private swizzled LDS (no cross-wave barrier needed)
#pragma unroll
    for (int n = 0; n < 4; ++n)
#pragma unroll
      for (int r = 0; r < 4; ++r) {
        int q = g * 4 + r;
        int kvv = n * 16 + lr;
        Pl[w][q * 64 + (((kvv >> 3) ^ (q & 7)) * 8) + (kvv & 7)] = f2bf(p[n][r]);
      }

    // O += P V
#pragma unroll
    for (int kk = 0; kk < 2; ++kk) {
      u16x8 pf = *(const u16x8*)&Pl[w][lr * 64 + (((kk * 4 + g) ^ (lr & 7)) * 8)];
#pragma unroll
      for (int dt = 0; dt < 4; ++dt) {
        int vr = dt * 16 + lr;
        u16x8 vf = *(const u16x8*)&Vc[vr * 64 + (((kk * 4 + g) ^ (vr & 7)) * 8)];
        o[dt] = mfma16(pf, vf, o[dt]);
      }
    }
    __syncthreads();   // single barrier: drains prefetch vmcnt + protects buffers
    cur ^= 1;
  }

  // epilogue: y = O / l, store bf16 [b*2048+t][h*64+d]
#pragma unroll
  for (int dt = 0; dt < 4; ++dt) {
#pragma unroll
    for (int r = 0; r < 4; ++r) {
      int t = q0 + g * 4 + r;
      int d = dt * 16 + lr;
      yb[((size_t)b_ * 2048 + t) * 1024 + h * 64 + d] = f2bf(o[dt][r] / lrow[r]);
    }
  }
}

// ---------------- GEMM2: out = y @ W_proj + b_proj (fp32 out) ----------------
__global__ void k_gemm_out(const u16* __restrict__ A, const u16* __restrict__ Bt,
                           const float* __restrict__ bias, float* __restrict__ out) {
  __shared__ u16 Al[128 * 64];
  __shared__ u16 Bl[128 * 64];
  const int tid = threadIdx.x;
  const int lane = tid & 63;
  const int w = tid >> 6;
  const int m0 = blockIdx.y * 128;
  const int n0 = blockIdx.x * 128;
  const int wr = (w >> 1) * 64;
  const int wc = (w & 1) * 64;
  const int lr = lane & 15;
  const int lk = (lane >> 4) * 8;

  f32x4 acc[4][4] = {};

  for (int k0 = 0; k0 < 1024; k0 += 64) {
#pragma unroll
    for (int it = 0; it < 4; ++it) {
      int off = (it * 256 + tid) * 8;
      int r = off >> 6, c = off & 63;
      gl_lds16(&A[(size_t)(m0 + r) * 1024 + k0 + c], &Al[off]);
      gl_lds16(&Bt[(size_t)(n0 + r) * 1024 + k0 + c], &Bl[off]);
    }
    __syncthreads();
#pragma unroll
    for (int kk = 0; kk < 64; kk += 32) {
      u16x8 af[4], bf[4];
#pragma unroll
      for (int i = 0; i < 4; ++i) {
        af[i] = *(const u16x8*)&Al[(wr + i * 16 + lr) * 64 + kk + lk];
        bf[i] = *(const u16x8*)&Bl[(wc + i * 16 + lr) * 64 + kk + lk];
      }
#pragma unroll
      for (int i = 0; i < 4; ++i)
#pragma unroll
        for (int j = 0; j < 4; ++j)
          acc[i][j] = mfma16(af[i], bf[j], acc[i][j]);
    }
    __syncthreads();
  }

#pragma unroll
  for (int i = 0; i < 4; ++i) {
    int rowb = m0 + wr + i * 16 + ((lane >> 4) << 2);
#pragma unroll
    for (int j = 0; j < 4; ++j) {
      int col = n0 + wc + j * 16 + lr;
      float bv = bias[col];
#pragma unroll
      for (int r = 0; r < 4; ++r)
        out[(size_t)(rowb + r) * 1024 + col] = acc[i][j][r] + bv;
    }
  }
}

extern "C" void kernel_launch(void* const* d_in, const int* in_sizes, int n_in,
                              void* d_out, int out_size, void* d_ws, size_t ws_size,
                              hipStream_t stream) {
  const float* x      = (const float*)d_in[0];
  const float* W_attn = (const float*)d_in[1];
  const float* b_attn = (const float*)d_in[2];
  const float* W_proj = (const float*)d_in[3];
  const float* b_proj = (const float*)d_in[4];
  float* out = (float*)d_out;

  char* ws = (char*)d_ws;
  const size_t MB = 1024 * 1024;
  u16* x_bf  = (u16*)(ws);             // 4096*1024   (8 MB)
  u16* Wt_a  = (u16*)(ws + 8 * MB);    // 3072*1024   (6 MB)
  u16* Wt_p  = (u16*)(ws + 14 * MB);   // 1024*1024   (2 MB)
  u16* qbf   = (u16*)(ws + 16 * MB);   // 32*2048*64  (8 MB)
  u16* kbf   = (u16*)(ws + 24 * MB);   // 32*2048*64  (8 MB)
  u16* vTbf  = (u16*)(ws + 32 * MB);   // 32*64*2048  (8 MB)
  u16* ybf   = (u16*)(ws + 40 * MB);   // 4096*1024   (8 MB)

  k_convert<<<2048, 256, 0, stream>>>(x, x_bf, 4096 * 1024);
  k_transpose<<<dim3(96, 32), dim3(32, 8), 0, stream>>>(W_attn, Wt_a, 1024, 3072);
  k_transpose<<<dim3(32, 32), dim3(32, 8), 0, stream>>>(W_proj, Wt_p, 1024, 1024);
  k_gemm_qkv<<<dim3(24, 32), 256, 0, stream>>>(x_bf, Wt_a, b_attn, qbf, kbf, vTbf);
  k_attn<<<dim3(32, 32), 256, 0, stream>>>(qbf, kbf, vTbf, ybf);
  k_gemm_out<<<dim3(8, 32), 256, 0, stream>>>(ybf, Wt_p, b_proj, out);
}

// Round 3
// 151.033 us; speedup vs baseline: 1.5062x; 1.2404x over previous
//
#include <hip/hip_runtime.h>

typedef unsigned short u16;
typedef float f32x4 __attribute__((ext_vector_type(4)));
typedef __bf16 bf16x8 __attribute__((ext_vector_type(8)));
typedef u16 u16x8 __attribute__((ext_vector_type(8)));

#define ATT_SCALE 0.0125f  // 0.1 / sqrt(64)
#define LOG2E 1.4426950408889634f

__device__ __forceinline__ u16 f2bf(float x) {
  unsigned u = __builtin_bit_cast(unsigned, x);
  u += 0x7fffu + ((u >> 16) & 1u);  // RNE
  return (u16)(u >> 16);
}

__device__ __forceinline__ float fexp2(float x) {
  return __builtin_amdgcn_exp2f(x);  // v_exp_f32: 2^x
}

__device__ __forceinline__ f32x4 mfma16(u16x8 a, u16x8 b, f32x4 c) {
  return __builtin_amdgcn_mfma_f32_16x16x32_bf16(
      __builtin_bit_cast(bf16x8, a), __builtin_bit_cast(bf16x8, b), c, 0, 0, 0);
}

__device__ __forceinline__ void gl_lds16(const void* g, void* l) {
  __builtin_amdgcn_global_load_lds(
      (__attribute__((address_space(1))) void*)g,
      (__attribute__((address_space(3))) void*)l, 16, 0, 0);
}

// ---------------- convert fp32 -> bf16 ----------------
__global__ void k_convert(const float* __restrict__ in, u16* __restrict__ out, int n) {
  int stride = gridDim.x * blockDim.x * 4;
  for (int i = (blockIdx.x * blockDim.x + threadIdx.x) * 4; i < n; i += stride) {
    float4 v = *(const float4*)&in[i];
    ushort4 o;
    o.x = f2bf(v.x); o.y = f2bf(v.y); o.z = f2bf(v.z); o.w = f2bf(v.w);
    *(ushort4*)&out[i] = o;
  }
}

// ---------------- transpose fp32[rows][cols] -> bf16[cols][rows] ----------------
__global__ void k_transpose(const float* __restrict__ in, u16* __restrict__ out,
                            int rows, int cols) {
  __shared__ float tile[32][33];
  int n0 = blockIdx.x * 32;  // col block
  int k0 = blockIdx.y * 32;  // row block
  int tx = threadIdx.x, ty = threadIdx.y;  // (32, 8)
#pragma unroll
  for (int i = 0; i < 32; i += 8)
    tile[ty + i][tx] = in[(size_t)(k0 + ty + i) * cols + n0 + tx];
  __syncthreads();
#pragma unroll
  for (int i = 0; i < 32; i += 8)
    out[(size_t)(n0 + ty + i) * rows + k0 + tx] = f2bf(tile[tx][ty + i]);
}

// ---------------- GEMM1: qkv = x @ W_attn + b_attn, scatter to q/k/vT bf16 ----------------
// Q is pre-scaled by ATT_SCALE*log2(e) (attention works in exp2 domain).
__global__ void k_gemm_qkv(const u16* __restrict__ A, const u16* __restrict__ Bt,
                           const float* __restrict__ bias,
                           u16* __restrict__ qb, u16* __restrict__ kb, u16* __restrict__ vTb) {
  __shared__ u16 Al[128 * 64];
  __shared__ u16 Bl[128 * 64];
  const int tid = threadIdx.x;
  const int lane = tid & 63;
  const int w = tid >> 6;
  const int m0 = blockIdx.y * 128;
  const int n0 = blockIdx.x * 128;
  const int wr = (w >> 1) * 64;
  const int wc = (w & 1) * 64;
  const int lr = lane & 15;
  const int lk = (lane >> 4) * 8;

  f32x4 acc[4][4] = {};

  for (int k0 = 0; k0 < 1024; k0 += 64) {
#pragma unroll
    for (int it = 0; it < 4; ++it) {
      int off = (it * 256 + tid) * 8;
      int r = off >> 6, c = off & 63;
      gl_lds16(&A[(size_t)(m0 + r) * 1024 + k0 + c], &Al[off]);
      gl_lds16(&Bt[(size_t)(n0 + r) * 1024 + k0 + c], &Bl[off]);
    }
    __syncthreads();
#pragma unroll
    for (int kk = 0; kk < 64; kk += 32) {
      u16x8 af[4], bf[4];
#pragma unroll
      for (int i = 0; i < 4; ++i) {
        af[i] = *(const u16x8*)&Al[(wr + i * 16 + lr) * 64 + kk + lk];
        bf[i] = *(const u16x8*)&Bl[(wc + i * 16 + lr) * 64 + kk + lk];
      }
#pragma unroll
      for (int i = 0; i < 4; ++i)
#pragma unroll
        for (int j = 0; j < 4; ++j)
          acc[i][j] = mfma16(af[i], bf[j], acc[i][j]);
    }
    __syncthreads();
  }

#pragma unroll
  for (int i = 0; i < 4; ++i) {
    int rowb = m0 + wr + i * 16 + ((lane >> 4) << 2);
#pragma unroll
    for (int j = 0; j < 4; ++j) {
      int col = n0 + wc + j * 16 + lr;
      float bv = bias[col];
      int which = col >> 10;
      int c = col & 1023;
      int h = c >> 6, d = c & 63;
#pragma unroll
      for (int r = 0; r < 4; ++r) {
        int row = rowb + r;
        int b_ = row >> 11, t = row & 2047;
        int bh = b_ * 16 + h;
        float fv = acc[i][j][r] + bv;
        if (which == 0) {
          qb[((size_t)bh * 2048 + t) * 64 + d] = f2bf(fv * (ATT_SCALE * LOG2E));
        } else if (which == 1) {
          kb[((size_t)bh * 2048 + t) * 64 + d] = f2bf(fv);
        } else {
          vTb[((size_t)bh * 64 + d) * 2048 + t] = f2bf(fv);
        }
      }
    }
  }
}

// ---------------- flash attention ----------------
// qb,kb: [32][2048][64] bf16 ; vTb: [32][64][2048] bf16 ; yb: [4096][1024] bf16
// K/V/P LDS tiles XOR-swizzled: 16B chunk c at row r holds global chunk c^(r&7).
// Block = (pair, bh): processes q-tiles pair and 31-pair -> constant 33 KV tiles/block.
__device__ __forceinline__ void stage_kv(const u16* __restrict__ kb_bh,
                                         const u16* __restrict__ vT_bh,
                                         u16* Kd, u16* Vd, int kv0, int tid) {
#pragma unroll
  for (int it = 0; it < 2; ++it) {
    int ch = it * 256 + tid;          // 16B-chunk index 0..511 (64 rows x 8 chunks)
    int r = ch >> 3, c = ch & 7;
    int sc = c ^ (r & 7);             // pre-swizzled global source chunk
    gl_lds16(&kb_bh[(size_t)(kv0 + r) * 64 + sc * 8], &Kd[ch * 8]);
    gl_lds16(&vT_bh[(size_t)r * 2048 + kv0 + sc * 8], &Vd[ch * 8]);
  }
}

__global__ void k_attn(const u16* __restrict__ qb, const u16* __restrict__ kb,
                       const u16* __restrict__ vTb, u16* __restrict__ yb) {
  __shared__ u16 Kl[2][4096];
  __shared__ u16 Vl[2][4096];      // transposed [d][kv]
  __shared__ u16 Pl[4][1024];      // per-wave [16 q][64 kv], swizzled

  const int tid = threadIdx.x, lane = tid & 63, w = tid >> 6;
  const int pairi = blockIdx.x;    // 0..15
  const int bh = blockIdx.y;       // 0..31
  const int b_ = bh >> 4, h = bh & 15;
  const int lr = lane & 15;
  const int g = lane >> 4;
  const int lk = g * 8;

  const u16* kb_bh = kb + (size_t)bh * 2048 * 64;
  const u16* vT_bh = vTb + (size_t)bh * 64 * 2048;

#pragma unroll 1
  for (int phase = 0; phase < 2; ++phase) {
    const int qt = phase ? (31 - pairi) : pairi;
    const int q0 = qt * 64 + w * 16;  // wave's first q row

    const u16* qrow = qb + ((size_t)bh * 2048 + q0 + lr) * 64;
    u16x8 qf[2];
    qf[0] = *(const u16x8*)&qrow[lk];
    qf[1] = *(const u16x8*)&qrow[32 + lk];

    f32x4 o[4] = {};
    float mrow[4], lrow[4];
#pragma unroll
    for (int r = 0; r < 4; ++r) { mrow[r] = -1e30f; lrow[r] = 0.f; }

    const int nkv = qt + 1;
    stage_kv(kb_bh, vT_bh, Kl[0], Vl[0], 0, tid);
    __syncthreads();
    int cur = 0;

    for (int kv = 0; kv < nkv; ++kv) {
      if (kv + 1 < nkv)
        stage_kv(kb_bh, vT_bh, Kl[cur ^ 1], Vl[cur ^ 1], (kv + 1) * 64, tid);

      const u16* Kc = Kl[cur];
      const u16* Vc = Vl[cur];

      // S = Q K^T   (16 q-rows x 64 keys per wave), in log2 domain
      f32x4 s[4] = {};
#pragma unroll
      for (int kk = 0; kk < 2; ++kk) {
#pragma unroll
        for (int n = 0; n < 4; ++n) {
          int kr = n * 16 + lr;
          u16x8 kf = *(const u16x8*)&Kc[kr * 64 + (((kk * 4 + g) ^ (kr & 7)) * 8)];
          s[n] = mfma16(qf[kk], kf, s[n]);
        }
      }

      // online softmax (exp2 domain; causal mask only on the diagonal tile)
      float p[4][4], tmax[4];
#pragma unroll
      for (int r = 0; r < 4; ++r) tmax[r] = -1e30f;
      if (kv == qt) {
#pragma unroll
        for (int n = 0; n < 4; ++n) {
          int kvg = kv * 64 + n * 16 + lr;
#pragma unroll
          for (int r = 0; r < 4; ++r) {
            int qg = q0 + g * 4 + r;
            float v = (kvg <= qg) ? s[n][r] : -1e30f;
            p[n][r] = v;
            tmax[r] = fmaxf(tmax[r], v);
          }
        }
      } else {
#pragma unroll
        for (int n = 0; n < 4; ++n)
#pragma unroll
          for (int r = 0; r < 4; ++r) {
            p[n][r] = s[n][r];
            tmax[r] = fmaxf(tmax[r], s[n][r]);
          }
      }
#pragma unroll
      for (int mks = 1; mks < 16; mks <<= 1)
#pragma unroll
        for (int r = 0; r < 4; ++r) tmax[r] = fmaxf(tmax[r], __shfl_xor(tmax[r], mks, 64));

      // defer-max (T13): only rescale when the running max grew by > 8 (2^8 headroom)
      bool grow = false;
#pragma unroll
      for (int r = 0; r < 4; ++r) grow = grow || (tmax[r] > mrow[r] + 8.0f);
      if (__any(grow)) {
#pragma unroll
        for (int r = 0; r < 4; ++r) {
          float mn = fmaxf(mrow[r], tmax[r]);
          float a = fexp2(mrow[r] - mn);
          mrow[r] = mn;
          lrow[r] *= a;
#pragma unroll
          for (int dt = 0; dt < 4; ++dt) o[dt][r] *= a;
        }
      }

      // P = exp2(S - m); lrow accumulates LANE-PARTIAL sums (reduced once at end)
#pragma unroll
      for (int n = 0; n < 4; ++n)
#pragma unroll
        for (int r = 0; r < 4; ++r) {
          float e = fexp2(p[n][r] - mrow[r]);
          lrow[r] += e;
          int q = g * 4 + r;
          int kvv = n * 16 + lr;
          Pl[w][q * 64 + (((kvv >> 3) ^ (q & 7)) * 8) + (kvv & 7)] = f2bf(e);
        }

      // O += P V
#pragma unroll
      for (int kk = 0; kk < 2; ++kk) {
        u16x8 pf = *(const u16x8*)&Pl[w][lr * 64 + (((kk * 4 + g) ^ (lr & 7)) * 8)];
#pragma unroll
        for (int dt = 0; dt < 4; ++dt) {
          int vr = dt * 16 + lr;
          u16x8 vf = *(const u16x8*)&Vc[vr * 64 + (((kk * 4 + g) ^ (vr & 7)) * 8)];
          o[dt] = mfma16(pf, vf, o[dt]);
        }
      }
      __syncthreads();   // single barrier: drains prefetch vmcnt + protects buffers
      cur ^= 1;
    }

    // epilogue: reduce lane-partial lrow across the 16-lane group, then y = O/l
#pragma unroll
    for (int mks = 1; mks < 16; mks <<= 1)
#pragma unroll
      for (int r = 0; r < 4; ++r) lrow[r] += __shfl_xor(lrow[r], mks, 64);

#pragma unroll
    for (int dt = 0; dt < 4; ++dt) {
#pragma unroll
      for (int r = 0; r < 4; ++r) {
        int t = q0 + g * 4 + r;
        int d = dt * 16 + lr;
        yb[((size_t)b_ * 2048 + t) * 1024 + h * 64 + d] = f2bf(o[dt][r] / lrow[r]);
      }
    }
  }
}

// ---------------- GEMM2: out = y @ W_proj + b_proj (fp32 out) ----------------
__global__ void k_gemm_out(const u16* __restrict__ A, const u16* __restrict__ Bt,
                           const float* __restrict__ bias, float* __restrict__ out) {
  __shared__ u16 Al[128 * 64];
  __shared__ u16 Bl[128 * 64];
  const int tid = threadIdx.x;
  const int lane = tid & 63;
  const int w = tid >> 6;
  const int m0 = blockIdx.y * 128;
  const int n0 = blockIdx.x * 128;
  const int wr = (w >> 1) * 64;
  const int wc = (w & 1) * 64;
  const int lr = lane & 15;
  const int lk = (lane >> 4) * 8;

  f32x4 acc[4][4] = {};

  for (int k0 = 0; k0 < 1024; k0 += 64) {
#pragma unroll
    for (int it = 0; it < 4; ++it) {
      int off = (it * 256 + tid) * 8;
      int r = off >> 6, c = off & 63;
      gl_lds16(&A[(size_t)(m0 + r) * 1024 + k0 + c], &Al[off]);
      gl_lds16(&Bt[(size_t)(n0 + r) * 1024 + k0 + c], &Bl[off]);
    }
    __syncthreads();
#pragma unroll
    for (int kk = 0; kk < 64; kk += 32) {
      u16x8 af[4], bf[4];
#pragma unroll
      for (int i = 0; i < 4; ++i) {
        af[i] = *(const u16x8*)&Al[(wr + i * 16 + lr) * 64 + kk + lk];
        bf[i] = *(const u16x8*)&Bl[(wc + i * 16 + lr) * 64 + kk + lk];
      }
#pragma unroll
      for (int i = 0; i < 4; ++i)
#pragma unroll
        for (int j = 0; j < 4; ++j)
          acc[i][j] = mfma16(af[i], bf[j], acc[i][j]);
    }
    __syncthreads();
  }

#pragma unroll
  for (int i = 0; i < 4; ++i) {
    int rowb = m0 + wr + i * 16 + ((lane >> 4) << 2);
#pragma unroll
    for (int j = 0; j < 4; ++j) {
      int col = n0 + wc + j * 16 + lr;
      float bv = bias[col];
#pragma unroll
      for (int r = 0; r < 4; ++r)
        out[(size_t)(rowb + r) * 1024 + col] = acc[i][j][r] + bv;
    }
  }
}

extern "C" void kernel_launch(void* const* d_in, const int* in_sizes, int n_in,
                              void* d_out, int out_size, void* d_ws, size_t ws_size,
                              hipStream_t stream) {
  const float* x      = (const float*)d_in[0];
  const float* W_attn = (const float*)d_in[1];
  const float* b_attn = (const float*)d_in[2];
  const float* W_proj = (const float*)d_in[3];
  const float* b_proj = (const float*)d_in[4];
  float* out = (float*)d_out;

  char* ws = (char*)d_ws;
  const size_t MB = 1024 * 1024;
  u16* x_bf  = (u16*)(ws);             // 4096*1024   (8 MB)
  u16* Wt_a  = (u16*)(ws + 8 * MB);    // 3072*1024   (6 MB)
  u16* Wt_p  = (u16*)(ws + 14 * MB);   // 1024*1024   (2 MB)
  u16* qbf   = (u16*)(ws + 16 * MB);   // 32*2048*64  (8 MB)
  u16* kbf   = (u16*)(ws + 24 * MB);   // 32*2048*64  (8 MB)
  u16* vTbf  = (u16*)(ws + 32 * MB);   // 32*64*2048  (8 MB)
  u16* ybf   = (u16*)(ws + 40 * MB);   // 4096*1024   (8 MB)

  k_convert<<<2048, 256, 0, stream>>>(x, x_bf, 4096 * 1024);
  k_transpose<<<dim3(96, 32), dim3(32, 8), 0, stream>>>(W_attn, Wt_a, 1024, 3072);
  k_transpose<<<dim3(32, 32), dim3(32, 8), 0, stream>>>(W_proj, Wt_p, 1024, 1024);
  k_gemm_qkv<<<dim3(24, 32), 256, 0, stream>>>(x_bf, Wt_a, b_attn, qbf, kbf, vTbf);
  k_attn<<<dim3(16, 32), 256, 0, stream>>>(qbf, kbf, vTbf, ybf);
  k_gemm_out<<<dim3(8, 32), 256, 0, stream>>>(ybf, Wt_p, b_proj, out);
}